// Round 10
// baseline (194.984 us; speedup 1.0000x reference)
//
#include <hip/hip_runtime.h>
#include <hip/hip_fp16.h>

#define LEAK 0.2f
#define CAP 64
#define CS 16   // cnt stride (ints): one counter per 64B line (atomic spread)

// swizzled sWf addressing: logical (c, j) -> 2-way-max bank aliasing (free)
static __device__ inline int swz(int c, int j) {
    int qb = j >> 3, r = j & 7;
    return c * 144 + qb * 8 + (qb >> 2) * 4 + r;
}
// offset-binary int8 quant of 4 floats (stored = round(v*is)+128 in [0,255])
static __device__ inline unsigned q4(float4 v, float is) {
    int x0 = __float2int_rn(v.x * is) + 128; x0 = min(max(x0, 0), 255);
    int x1 = __float2int_rn(v.y * is) + 128; x1 = min(max(x1, 0), 255);
    int x2 = __float2int_rn(v.z * is) + 128; x2 = min(max(x2, 0), 255);
    int x3 = __float2int_rn(v.w * is) + 128; x3 = min(max(x3, 0), 255);
    return (unsigned)x0 | ((unsigned)x1 << 8) | ((unsigned)x2 << 16) | ((unsigned)x3 << 24);
}

// =========================================================================
// k0: [zero cnt | pack pk=dst<<16|src | fold W2 -> WfT, bc]. (r6 version)
// =========================================================================
__global__ __launch_bounds__(256) void k0(
    int* __restrict__ cnt,
    const int* __restrict__ src, const int* __restrict__ dst,
    unsigned* __restrict__ pk,
    const float* __restrict__ W2, const float* __restrict__ al2,
    const float* __restrict__ ar2, const float* __restrict__ fcW,
    const float* __restrict__ b2, float* __restrict__ WfT,
    float* __restrict__ bc, int N, int E, int zb, int pkb) {
    const int b = blockIdx.x;
    const int t = threadIdx.x;
    if (b < zb) {
        int i = b * 256 + t;                  // int4 index into cnt
        if (i < N * (CS / 4)) ((int4*)cnt)[i] = make_int4(0, 0, 0, 0);
        return;
    }
    if (b < zb + pkb) {
        int i = (b - zb) * 256 + t;           // quad index into pk
        int e0 = i * 4;
        if (e0 + 3 < E) {
            int4 d = ((const int4*)dst)[i];
            int4 s = ((const int4*)src)[i];
            ((int4*)pk)[i] = make_int4((d.x << 16) | s.x, (d.y << 16) | s.y,
                                       (d.z << 16) | s.z, (d.w << 16) | s.w);
        } else if (e0 < E) {
            for (int e = e0; e < E; e++) pk[e] = ((unsigned)dst[e] << 16) | (unsigned)src[e];
        }
        return;
    }
    int idx = (b - zb - pkb) * 256 + t;
    if (idx < 1536) {
        int c = idx >> 7, k = idx & 127;
        int h = c & 3, sel = c >> 2;
        const float* vec = (sel == 0) ? (al2 + 32 * h)
                         : (sel == 1) ? (ar2 + 32 * h) : fcW;
        float s = 0.f;
#pragma unroll 8
        for (int m = 0; m < 32; m++) s += W2[k * 128 + 32 * h + m] * vec[m];
        WfT[c * 128 + k] = s;
    } else if (idx < 1540) {
        int h = idx - 1536;
        float s = 0.f;
        for (int m = 0; m < 32; m++) s += b2[h * 32 + m] * fcW[m];
        bc[h] = s;
    }
}

// =========================================================================
// k_eg: INTERLEAVED [ELL build || GEMM], octet-granular Bresenham mix —
// exact r6 version (best measured: 184.8 total). r7 BK=16: neutral.
// r8 bucketing: -19us regression (ELL is atomic-floor-bound, not scan-BW).
// r9 chaining: zero overlap (uniform phase durations serialize). ELL floor
// ~35-38us is thread-count-invariant 768->2048 blocks: L2 atomic
// throughput + ~16 same-address atomics/node serialization. Keep r6.
// =========================================================================
__global__ __launch_bounds__(256, 4) void k_eg(
    const float* __restrict__ X, const float* __restrict__ W,
    const float* __restrict__ al, const float* __restrict__ ar,
    float2* __restrict__ elsc2, float* __restrict__ er_nh,
    unsigned* __restrict__ fq8,
    const unsigned* __restrict__ pk,
    int* __restrict__ cnt, unsigned short* __restrict__ ell,
    int N, int E, int R, int GO, int T) {
    __shared__ float sW[32 * 128];
    __shared__ float sXT[32 * 64];
    const int b = blockIdx.x;
    const int t = threadIdx.x;
    const int o = b >> 3;
    const int g0 = (o * GO) / T;
    const bool isGemm = ((o + 1) * GO) / T > g0;

    if (!isGemm) {
        // ---- ELL build (XCD-partitioned; cnt padded 1 counter / 64B line)
        const int part = b & 7;
        const int rank = o - g0;             // covers [0, R) bijectively
        const int S = (N + 7) >> 3;
        const int lo = part * S;
        const int hi = (lo + S < N) ? (lo + S) : N;
        const int per = (E + R - 1) / R;
        const int e0 = rank * per;
        const int e1 = (e0 + per < E) ? (e0 + per) : E;
        int e = e0 + t;
        for (; e + 768 < e1; e += 1024) {
            unsigned p0 = pk[e];       unsigned p1 = pk[e + 256];
            unsigned p2 = pk[e + 512]; unsigned p3 = pk[e + 768];
            int d0 = (int)(p0 >> 16), d1 = (int)(p1 >> 16);
            int d2 = (int)(p2 >> 16), d3 = (int)(p3 >> 16);
            if (d0 >= lo && d0 < hi) {
                int pos = atomicAdd(&cnt[d0 * CS], 1);
                if (pos < CAP) ell[(size_t)d0 * CAP + pos] = (unsigned short)(p0 & 0xffffu);
            }
            if (d1 >= lo && d1 < hi) {
                int pos = atomicAdd(&cnt[d1 * CS], 1);
                if (pos < CAP) ell[(size_t)d1 * CAP + pos] = (unsigned short)(p1 & 0xffffu);
            }
            if (d2 >= lo && d2 < hi) {
                int pos = atomicAdd(&cnt[d2 * CS], 1);
                if (pos < CAP) ell[(size_t)d2 * CAP + pos] = (unsigned short)(p2 & 0xffffu);
            }
            if (d3 >= lo && d3 < hi) {
                int pos = atomicAdd(&cnt[d3 * CS], 1);
                if (pos < CAP) ell[(size_t)d3 * CAP + pos] = (unsigned short)(p3 & 0xffffu);
            }
        }
        for (; e < e1; e += 256) {
            unsigned p = pk[e];
            int d = (int)(p >> 16);
            if (d >= lo && d < hi) {
                int pos = atomicAdd(&cnt[d * CS], 1);
                if (pos < CAP) ell[(size_t)d * CAP + pos] = (unsigned short)(p & 0xffffu);
            }
        }
        return;
    }

    // ---- GEMM: 64 rows x 128 cols per block, BK=32, XOR-swizzled sXT.
    const int tile = g0 * 8 + (b & 7);
    const int r0 = tile * 64;
    if (r0 >= N) return;                      // tail octet padding
    const int tx = t & 15;
    const int ty = t >> 4;
    const float4* X4 = (const float4*)X;
    const float4* W4 = (const float4*)W;
    float4* sW4 = (float4*)sW;
    const float4* sXT4 = (const float4*)sXT;

    float4 acc[4][2];
#pragma unroll
    for (int r = 0; r < 4; r++) {
        acc[r][0] = make_float4(0.f, 0.f, 0.f, 0.f);
        acc[r][1] = make_float4(0.f, 0.f, 0.f, 0.f);
    }
    for (int ks = 0; ks < 4; ++ks) {
        if (ks) __syncthreads();
#pragma unroll
        for (int i = 0; i < 4; i++) {
            int idx = i * 256 + t;
            sW4[idx] = W4[1024 * ks + idx];
        }
#pragma unroll
        for (int i = 0; i < 2; i++) {
            int idx = i * 256 + t;
            int row = idx >> 3;
            int kq = idx & 7;
            float4 v = make_float4(0.f, 0.f, 0.f, 0.f);
            if (r0 + row < N) v = X4[(size_t)(r0 + row) * 32 + ks * 8 + kq];
            int sc = ((row >> 2) ^ kq) * 4 + (row & 3);
            sXT[(4 * kq + 0) * 64 + sc] = v.x;
            sXT[(4 * kq + 1) * 64 + sc] = v.y;
            sXT[(4 * kq + 2) * 64 + sc] = v.z;
            sXT[(4 * kq + 3) * 64 + sc] = v.w;
        }
        __syncthreads();
#pragma unroll 4
        for (int k = 0; k < 32; k++) {
            float4 w0 = sW4[k * 32 + tx];
            float4 w1 = sW4[k * 32 + 16 + tx];
            float4 x0 = sXT4[k * 16 + (ty ^ (k >> 2))];
            float xs[4] = {x0.x, x0.y, x0.z, x0.w};
#pragma unroll
            for (int r = 0; r < 4; r++) {
                acc[r][0].x += xs[r] * w0.x; acc[r][0].y += xs[r] * w0.y;
                acc[r][0].z += xs[r] * w0.z; acc[r][0].w += xs[r] * w0.w;
                acc[r][1].x += xs[r] * w1.x; acc[r][1].y += xs[r] * w1.y;
                acc[r][1].z += xs[r] * w1.z; acc[r][1].w += xs[r] * w1.w;
            }
        }
    }
    const float4* al4p = (const float4*)al;
    const float4* ar4p = (const float4*)ar;
    float4 alA = al4p[tx], alB = al4p[16 + tx];
    float4 arA = ar4p[tx], arB = ar4p[16 + tx];
#pragma unroll
    for (int r = 0; r < 4; r++) {
        int row = r0 + ty * 4 + r;
        bool ok = row < N;
        float4 a0 = acc[r][0], a1 = acc[r][1];
        float m = fmaxf(fmaxf(fmaxf(fabsf(a0.x), fabsf(a0.y)),
                              fmaxf(fabsf(a0.z), fabsf(a0.w))),
                        fmaxf(fmaxf(fabsf(a1.x), fabsf(a1.y)),
                              fmaxf(fabsf(a1.z), fabsf(a1.w))));
#pragma unroll
        for (int off = 1; off < 16; off <<= 1) m = fmaxf(m, __shfl_xor(m, off));
        float scale = m * (1.f / 127.f);
        float is = (m > 0.f) ? (127.f / m) : 0.f;
        if (ok) {
            fq8[(size_t)row * 32 + tx] = q4(a0, is);
            fq8[(size_t)row * 32 + 16 + tx] = q4(a1, is);
        }
        float elA = a0.x * alA.x + a0.y * alA.y + a0.z * alA.z + a0.w * alA.w;
        float erA = a0.x * arA.x + a0.y * arA.y + a0.z * arA.z + a0.w * arA.w;
        float elB = a1.x * alB.x + a1.y * alB.y + a1.z * alB.z + a1.w * alB.w;
        float erB = a1.x * arB.x + a1.y * arB.y + a1.z * arB.z + a1.w * arB.w;
#pragma unroll
        for (int off = 1; off < 8; off <<= 1) {
            elA += __shfl_xor(elA, off); erA += __shfl_xor(erA, off);
            elB += __shfl_xor(elB, off); erB += __shfl_xor(erB, off);
        }
        if (ok && tx == 0) {
            elsc2[row * 4 + 0] = make_float2(elA, scale);
            elsc2[row * 4 + 2] = make_float2(elB, scale);
            er_nh[row * 4 + 0] = erA;
            er_nh[row * 4 + 2] = erB;
        }
        if (ok && tx == 8) {
            elsc2[row * 4 + 1] = make_float2(elA, scale);
            elsc2[row * 4 + 3] = make_float2(elB, scale);
            er_nh[row * 4 + 1] = erA;
            er_nh[row * 4 + 3] = erB;
        }
    }
}

// =========================================================================
// k_agg1P: layer-1 aggregation + fused P-projection, TWO COLUMN-HALF
// PASSES. Theory: fq8 (6.4MB) > 4MB per-XCD L2 -> E x 128B random gathers
// (~102MB) thrash L2 and fall to L3 (~2.6 TB/s observed-equivalent).
// Pass p touches ONLY the p-th 64B line of each row (lane q gathers the
// 4B covering cols 64p+4q..+3): per-pass line working set = 3.2MB ->
// L2-resident. Edges scanned twice (reg shfl + L2-resident elsc2 + cheap
// exp = minor). Per-column acc order, den, hv bitwise-identical to r6;
// only the P-projection lane grouping reassociates (~1 ulp, absorbed by
// the 2^-10 quant-error absmax).
// Lane q, pass p: h = 2p + (q>>3); cols 64p+4q..+3; sWf offsets w0 (pass0)
// and w0+72 (pass1), both float4-aligned, <=2-way bank aliasing.
// =========================================================================
__global__ __launch_bounds__(256) void k_agg1P(
    const unsigned* __restrict__ fq8, const float2* __restrict__ elsc2,
    const float* __restrict__ er_nh, const unsigned short* __restrict__ ell,
    const int* __restrict__ cnt, const float* __restrict__ b1,
    const float* __restrict__ WfT, float2* __restrict__ Pag,
    float* __restrict__ er2, int N) {
    __shared__ float sWf[12 * 144];
    for (int i = threadIdx.x; i < 1536; i += 256)
        sWf[swz(i >> 7, i & 127)] = WfT[i];
    __syncthreads();
    const int wave = threadIdx.x >> 6, lane = threadIdx.x & 63;
    const int nsub = lane >> 4, q = lane & 15;

    const int n = blockIdx.x * 16 + wave * 4 + nsub;
    const bool nok = n < N;
    const int nc = nok ? n : (N - 1);
    int deg = nok ? cnt[nc * CS] : 0; if (deg > CAP) deg = CAP;
    const unsigned short* row = ell + (size_t)nc * CAP;
    uint2 rv = ((const uint2*)row)[q];   // entries 4q..4q+3 of this node's row

    float hv[8];
#pragma unroll
    for (int p = 0; p < 2; p++) {
        const int h = p * 2 + (q >> 3);
        const float er = nok ? er_nh[nc * 4 + h] : 0.f;
        float acc0 = 0.f, acc1 = 0.f, acc2 = 0.f, acc3 = 0.f;
        float den = 0.f, wss = 0.f;
        for (int j0 = 0; j0 < deg; j0 += 8) {
            int sv[8]; float2 esv[8]; unsigned fv[8];
#pragma unroll
            for (int v = 0; v < 8; v++) {
                int wrd = __shfl((int)((v & 2) ? rv.y : rv.x),
                                 (lane & 48) | ((j0 >> 2) + (v >> 2)));
                int s = (v & 1) ? ((wrd >> 16) & 0xffff) : (wrd & 0xffff);
                sv[v] = (j0 + v < deg) ? s : 0;
            }
#pragma unroll
            for (int v = 0; v < 8; v++) esv[v] = elsc2[sv[v] * 4 + h];
#pragma unroll
            for (int v = 0; v < 8; v++)
                fv[v] = fq8[(size_t)sv[v] * 32 + p * 16 + q];
#pragma unroll
            for (int v = 0; v < 8; v++) {
                bool valid = (j0 + v) < deg;
                float e = esv[v].x + er;
                e = fmaxf(e, LEAK * e);
                float w = valid ? __expf(e) : 0.f;
                float ws = w * esv[v].y;
                unsigned ua = fv[v];
                acc0 += ws * (float)(ua & 0xff);
                acc1 += ws * (float)((ua >> 8) & 0xff);
                acc2 += ws * (float)((ua >> 16) & 0xff);
                acc3 += ws * (float)(ua >> 24);
                den += w; wss += ws;
            }
        }
        float inv = (den > 0.f) ? (1.f / den) : 0.f;
        float off128 = 128.f * wss;
        float4 bb = ((const float4*)b1)[p * 16 + q];
        hv[p * 4 + 0] = fmaxf((acc0 - off128) * inv + bb.x, 0.f);
        hv[p * 4 + 1] = fmaxf((acc1 - off128) * inv + bb.y, 0.f);
        hv[p * 4 + 2] = fmaxf((acc2 - off128) * inv + bb.z, 0.f);
        hv[p * 4 + 3] = fmaxf((acc3 - off128) * inv + bb.w, 0.f);
    }
    const int w0 = (q >> 1) * 8 + (q >> 3) * 4 + (q & 1) * 4;
    float pr[12];
#pragma unroll
    for (int c = 0; c < 12; c++) {
        const float* wr = sWf + c * 144;
        float4 wa = *(const float4*)(wr + w0);
        float4 wb = *(const float4*)(wr + w0 + 72);
        pr[c] = hv[0] * wa.x + hv[1] * wa.y + hv[2] * wa.z + hv[3] * wa.w
              + hv[4] * wb.x + hv[5] * wb.y + hv[6] * wb.z + hv[7] * wb.w;
    }
#pragma unroll
    for (int off = 1; off < 16; off <<= 1) {
#pragma unroll
        for (int c = 0; c < 12; c++) pr[c] += __shfl_xor(pr[c], off);
    }
    if (nok) {
        if (q < 4) Pag[(size_t)n * 4 + q] = make_float2(pr[q], pr[8 + q]);
        else if (q < 8) er2[(size_t)n * 4 + (q - 4)] = pr[q];
    }
}

// =========================================================================
// k_agg2: thread per (node, head); full row in regs (r6 version).
// =========================================================================
__global__ __launch_bounds__(256) void k_agg2(
    const float2* __restrict__ Pag, const float* __restrict__ er2,
    const unsigned short* __restrict__ ell, const int* __restrict__ cnt,
    const float* __restrict__ bc, const float* __restrict__ fcb,
    float* __restrict__ out, int N) {
    int idx = blockIdx.x * 256 + threadIdx.x;
    int n = idx >> 2, h = idx & 3;
    if (n >= N) return;
    int deg = cnt[n * CS]; if (deg > CAP) deg = CAP;
    float er = er2[(size_t)n * 4 + h];
    const uint4* row4 = (const uint4*)(ell + (size_t)n * CAP);
    uint4 rv[8];
#pragma unroll
    for (int i = 0; i < 8; i++) rv[i] = row4[i];   // full row: 64 entries

    float num = 0.f, den = 0.f;
#pragma unroll
    for (int b8 = 0; b8 < 8; ++b8) {
        int j0 = b8 * 8;
        if (j0 >= deg) break;
        int sv[8];
#pragma unroll
        for (int v = 0; v < 8; v++) {
            unsigned wrd = ((v >> 1) == 0) ? rv[b8].x
                         : ((v >> 1) == 1) ? rv[b8].y
                         : ((v >> 1) == 2) ? rv[b8].z : rv[b8].w;
            int s = (v & 1) ? (int)(wrd >> 16) : (int)(wrd & 0xffffu);
            sv[v] = (j0 + v < deg) ? s : 0;
        }
        float2 g[8];
#pragma unroll
        for (int v = 0; v < 8; v++) g[v] = Pag[(size_t)sv[v] * 4 + h];
#pragma unroll
        for (int v = 0; v < 8; v++) {
            if (j0 + v < deg) {
                float e = g[v].x + er; e = fmaxf(e, LEAK * e);
                float w = __expf(e);
                num += w * g[v].y; den += w;
            }
        }
    }
    float r = (den > 0.f) ? (num / den) : 0.f;
    r += bc[h];
    r += __shfl_xor(r, 1);
    r += __shfl_xor(r, 2);
    if (h == 0) out[n] = 0.25f * r + fcb[0];
}

extern "C" void kernel_launch(void* const* d_in, const int* in_sizes, int n_in,
                              void* d_out, int out_size, void* d_ws, size_t ws_size,
                              hipStream_t stream) {
    const float* x   = (const float*)d_in[0];
    const int* src   = (const int*)d_in[1];
    const int* dst   = (const int*)d_in[2];
    const float* W1  = (const float*)d_in[3];
    const float* al1 = (const float*)d_in[4];
    const float* ar1 = (const float*)d_in[5];
    const float* b1  = (const float*)d_in[6];
    const float* W2  = (const float*)d_in[7];
    const float* al2 = (const float*)d_in[8];
    const float* ar2 = (const float*)d_in[9];
    const float* b2  = (const float*)d_in[10];
    const float* fcW = (const float*)d_in[11];
    const float* fcb = (const float*)d_in[12];
    float* out = (float*)d_out;

    const int N = in_sizes[0] / 128;   // 50000 (< 65536, required for ushort ELL/pk)
    const int E = in_sizes[1];

    char* w = (char*)d_ws;
    size_t off = 0;
    auto alloc = [&](size_t bytes) {
        void* p = w + off;
        off = (off + bytes + 255) & ~(size_t)255;
        return p;
    };
    unsigned* fq8  = (unsigned*)alloc((size_t)N * 32 * 4);   // int8 [N][128], 6.4 MB
    float2* elsc2  = (float2*)alloc((size_t)N * 4 * 8);      // {el_h, scale}
    float* er_nh   = (float*)alloc((size_t)N * 4 * 4);
    float2* Pag    = (float2*)alloc((size_t)N * 4 * 8);
    float* er2     = (float*)alloc((size_t)N * 4 * 4);
    float* WfT     = (float*)alloc((size_t)(12 * 128 + 4) * 4);
    float* bc      = WfT + 12 * 128;
    int* cnt       = (int*)alloc((size_t)N * CS * 4);        // padded: 64B/node
    unsigned short* ell = (unsigned short*)alloc((size_t)N * CAP * 2);
    unsigned* pk   = (unsigned*)alloc((size_t)E * 4);        // dst<<16|src, 3.2 MB

    const int zb = (N * (CS / 4) + 255) / 256;   // int4 stores over N*CS ints
    const int pkb = (E / 4 + 255) / 256;         // pack blocks
    const int gtiles = (N + 63) / 64;            // 64-row GEMM tiles
    const int R = 256;                           // ELL ranks (256 ELL octets)
    const int GO = (gtiles + 7) / 8;             // GEMM octets
    const int T = R + GO;                        // total octets

    k0<<<zb + pkb + 8, 256, 0, stream>>>(
        cnt, src, dst, pk, W2, al2, ar2, fcW, b2, WfT, bc, N, E, zb, pkb);
    k_eg<<<8 * T, 256, 0, stream>>>(
        x, W1, al1, ar1, elsc2, er_nh, fq8,
        pk, cnt, ell, N, E, R, GO, T);
    k_agg1P<<<(N + 15) / 16, 256, 0, stream>>>(
        fq8, elsc2, er_nh, ell, cnt, b1, WfT, Pag, er2, N);
    k_agg2<<<(N * 4 + 255) / 256, 256, 0, stream>>>(
        Pag, er2, ell, cnt, bc, fcb, out, N);
}

// Round 11
// 188.212 us; speedup vs baseline: 1.0360x; 1.0360x over previous
//
#include <hip/hip_runtime.h>
#include <hip/hip_fp16.h>

#define LEAK 0.2f
#define CAP 64
#define CS 16   // cnt stride (ints): one counter per 64B line (atomic spread)

// swizzled sWf addressing: logical (c, j) -> 2-way-max bank aliasing (free)
static __device__ inline int swz(int c, int j) {
    int qb = j >> 3, r = j & 7;
    return c * 144 + qb * 8 + (qb >> 2) * 4 + r;
}
// offset-binary int8 quant of 4 floats (stored = round(v*is)+128 in [0,255])
static __device__ inline unsigned q4(float4 v, float is) {
    int x0 = __float2int_rn(v.x * is) + 128; x0 = min(max(x0, 0), 255);
    int x1 = __float2int_rn(v.y * is) + 128; x1 = min(max(x1, 0), 255);
    int x2 = __float2int_rn(v.z * is) + 128; x2 = min(max(x2, 0), 255);
    int x3 = __float2int_rn(v.w * is) + 128; x3 = min(max(x3, 0), 255);
    return (unsigned)x0 | ((unsigned)x1 << 8) | ((unsigned)x2 << 16) | ((unsigned)x3 << 24);
}

// =========================================================================
// k0: [zero cnt | pack pk=dst<<16|src | fold W2 -> WfT, bc]. (r6 version —
// best measured config. Ledger of refuted alternatives: r8 radix bucketing
// -19us; r10 two-pass agg blocking -10us; r9 chaining -7us; r7 BK16 ~0.)
// =========================================================================
__global__ __launch_bounds__(256) void k0(
    int* __restrict__ cnt,
    const int* __restrict__ src, const int* __restrict__ dst,
    unsigned* __restrict__ pk,
    const float* __restrict__ W2, const float* __restrict__ al2,
    const float* __restrict__ ar2, const float* __restrict__ fcW,
    const float* __restrict__ b2, float* __restrict__ WfT,
    float* __restrict__ bc, int N, int E, int zb, int pkb) {
    const int b = blockIdx.x;
    const int t = threadIdx.x;
    if (b < zb) {
        int i = b * 256 + t;                  // int4 index into cnt
        if (i < N * (CS / 4)) ((int4*)cnt)[i] = make_int4(0, 0, 0, 0);
        return;
    }
    if (b < zb + pkb) {
        int i = (b - zb) * 256 + t;           // quad index into pk
        int e0 = i * 4;
        if (e0 + 3 < E) {
            int4 d = ((const int4*)dst)[i];
            int4 s = ((const int4*)src)[i];
            ((int4*)pk)[i] = make_int4((d.x << 16) | s.x, (d.y << 16) | s.y,
                                       (d.z << 16) | s.z, (d.w << 16) | s.w);
        } else if (e0 < E) {
            for (int e = e0; e < E; e++) pk[e] = ((unsigned)dst[e] << 16) | (unsigned)src[e];
        }
        return;
    }
    int idx = (b - zb - pkb) * 256 + t;
    if (idx < 1536) {
        int c = idx >> 7, k = idx & 127;
        int h = c & 3, sel = c >> 2;
        const float* vec = (sel == 0) ? (al2 + 32 * h)
                         : (sel == 1) ? (ar2 + 32 * h) : fcW;
        float s = 0.f;
#pragma unroll 8
        for (int m = 0; m < 32; m++) s += W2[k * 128 + 32 * h + m] * vec[m];
        WfT[c * 128 + k] = s;
    } else if (idx < 1540) {
        int h = idx - 1536;
        float s = 0.f;
        for (int m = 0; m < 32; m++) s += b2[h * 32 + m] * fcW[m];
        bc[h] = s;
    }
}

// =========================================================================
// k_eg: INTERLEAVED [ELL build || GEMM], octet-granular Bresenham mix —
// exact r6 version (best measured: 184.8 total; ~11us of ELL/GEMM overlap).
// ELL floor ~35us is a per-XCD L2 atomic-channel throughput floor: 800K
// RMWs through ~16 channels/XCD at ~10-15cy — invariant to thread count
// (768->2048 blocks, r8/r9), scan traffic (8x->1x, r8), LDS occupancy
// (r7), and block ordering (r1/r2/r9). part = b&7 == XCD keeps cnt/ell
// L2-local (r3: full-range atomics = 61us, 44.8MB HBM writes).
// GEMM: 64x128 tile, BK=32, XOR-swizzled sXT, LDS 24KB.
// __launch_bounds__(256,4): VGPR cap 128/wave (DO NOT raise).
// =========================================================================
__global__ __launch_bounds__(256, 4) void k_eg(
    const float* __restrict__ X, const float* __restrict__ W,
    const float* __restrict__ al, const float* __restrict__ ar,
    float2* __restrict__ elsc2, float* __restrict__ er_nh,
    unsigned* __restrict__ fq8,
    const unsigned* __restrict__ pk,
    int* __restrict__ cnt, unsigned short* __restrict__ ell,
    int N, int E, int R, int GO, int T) {
    __shared__ float sW[32 * 128];
    __shared__ float sXT[32 * 64];
    const int b = blockIdx.x;
    const int t = threadIdx.x;
    const int o = b >> 3;
    const int g0 = (o * GO) / T;
    const bool isGemm = ((o + 1) * GO) / T > g0;

    if (!isGemm) {
        // ---- ELL build (XCD-partitioned; cnt padded 1 counter / 64B line)
        const int part = b & 7;
        const int rank = o - g0;             // covers [0, R) bijectively
        const int S = (N + 7) >> 3;
        const int lo = part * S;
        const int hi = (lo + S < N) ? (lo + S) : N;
        const int per = (E + R - 1) / R;
        const int e0 = rank * per;
        const int e1 = (e0 + per < E) ? (e0 + per) : E;
        int e = e0 + t;
        for (; e + 768 < e1; e += 1024) {
            unsigned p0 = pk[e];       unsigned p1 = pk[e + 256];
            unsigned p2 = pk[e + 512]; unsigned p3 = pk[e + 768];
            int d0 = (int)(p0 >> 16), d1 = (int)(p1 >> 16);
            int d2 = (int)(p2 >> 16), d3 = (int)(p3 >> 16);
            if (d0 >= lo && d0 < hi) {
                int pos = atomicAdd(&cnt[d0 * CS], 1);
                if (pos < CAP) ell[(size_t)d0 * CAP + pos] = (unsigned short)(p0 & 0xffffu);
            }
            if (d1 >= lo && d1 < hi) {
                int pos = atomicAdd(&cnt[d1 * CS], 1);
                if (pos < CAP) ell[(size_t)d1 * CAP + pos] = (unsigned short)(p1 & 0xffffu);
            }
            if (d2 >= lo && d2 < hi) {
                int pos = atomicAdd(&cnt[d2 * CS], 1);
                if (pos < CAP) ell[(size_t)d2 * CAP + pos] = (unsigned short)(p2 & 0xffffu);
            }
            if (d3 >= lo && d3 < hi) {
                int pos = atomicAdd(&cnt[d3 * CS], 1);
                if (pos < CAP) ell[(size_t)d3 * CAP + pos] = (unsigned short)(p3 & 0xffffu);
            }
        }
        for (; e < e1; e += 256) {
            unsigned p = pk[e];
            int d = (int)(p >> 16);
            if (d >= lo && d < hi) {
                int pos = atomicAdd(&cnt[d * CS], 1);
                if (pos < CAP) ell[(size_t)d * CAP + pos] = (unsigned short)(p & 0xffffu);
            }
        }
        return;
    }

    // ---- GEMM: 64 rows x 128 cols per block, BK=32, XOR-swizzled sXT.
    const int tile = g0 * 8 + (b & 7);
    const int r0 = tile * 64;
    if (r0 >= N) return;                      // tail octet padding
    const int tx = t & 15;
    const int ty = t >> 4;
    const float4* X4 = (const float4*)X;
    const float4* W4 = (const float4*)W;
    float4* sW4 = (float4*)sW;
    const float4* sXT4 = (const float4*)sXT;

    float4 acc[4][2];
#pragma unroll
    for (int r = 0; r < 4; r++) {
        acc[r][0] = make_float4(0.f, 0.f, 0.f, 0.f);
        acc[r][1] = make_float4(0.f, 0.f, 0.f, 0.f);
    }
    for (int ks = 0; ks < 4; ++ks) {
        if (ks) __syncthreads();
#pragma unroll
        for (int i = 0; i < 4; i++) {
            int idx = i * 256 + t;
            sW4[idx] = W4[1024 * ks + idx];
        }
#pragma unroll
        for (int i = 0; i < 2; i++) {
            int idx = i * 256 + t;
            int row = idx >> 3;
            int kq = idx & 7;
            float4 v = make_float4(0.f, 0.f, 0.f, 0.f);
            if (r0 + row < N) v = X4[(size_t)(r0 + row) * 32 + ks * 8 + kq];
            int sc = ((row >> 2) ^ kq) * 4 + (row & 3);
            sXT[(4 * kq + 0) * 64 + sc] = v.x;
            sXT[(4 * kq + 1) * 64 + sc] = v.y;
            sXT[(4 * kq + 2) * 64 + sc] = v.z;
            sXT[(4 * kq + 3) * 64 + sc] = v.w;
        }
        __syncthreads();
#pragma unroll 4
        for (int k = 0; k < 32; k++) {
            float4 w0 = sW4[k * 32 + tx];
            float4 w1 = sW4[k * 32 + 16 + tx];
            float4 x0 = sXT4[k * 16 + (ty ^ (k >> 2))];
            float xs[4] = {x0.x, x0.y, x0.z, x0.w};
#pragma unroll
            for (int r = 0; r < 4; r++) {
                acc[r][0].x += xs[r] * w0.x; acc[r][0].y += xs[r] * w0.y;
                acc[r][0].z += xs[r] * w0.z; acc[r][0].w += xs[r] * w0.w;
                acc[r][1].x += xs[r] * w1.x; acc[r][1].y += xs[r] * w1.y;
                acc[r][1].z += xs[r] * w1.z; acc[r][1].w += xs[r] * w1.w;
            }
        }
    }
    const float4* al4p = (const float4*)al;
    const float4* ar4p = (const float4*)ar;
    float4 alA = al4p[tx], alB = al4p[16 + tx];
    float4 arA = ar4p[tx], arB = ar4p[16 + tx];
#pragma unroll
    for (int r = 0; r < 4; r++) {
        int row = r0 + ty * 4 + r;
        bool ok = row < N;
        float4 a0 = acc[r][0], a1 = acc[r][1];
        float m = fmaxf(fmaxf(fmaxf(fabsf(a0.x), fabsf(a0.y)),
                              fmaxf(fabsf(a0.z), fabsf(a0.w))),
                        fmaxf(fmaxf(fabsf(a1.x), fabsf(a1.y)),
                              fmaxf(fabsf(a1.z), fabsf(a1.w))));
#pragma unroll
        for (int off = 1; off < 16; off <<= 1) m = fmaxf(m, __shfl_xor(m, off));
        float scale = m * (1.f / 127.f);
        float is = (m > 0.f) ? (127.f / m) : 0.f;
        if (ok) {
            fq8[(size_t)row * 32 + tx] = q4(a0, is);
            fq8[(size_t)row * 32 + 16 + tx] = q4(a1, is);
        }
        float elA = a0.x * alA.x + a0.y * alA.y + a0.z * alA.z + a0.w * alA.w;
        float erA = a0.x * arA.x + a0.y * arA.y + a0.z * arA.z + a0.w * arA.w;
        float elB = a1.x * alB.x + a1.y * alB.y + a1.z * alB.z + a1.w * alB.w;
        float erB = a1.x * arB.x + a1.y * arB.y + a1.z * arB.z + a1.w * arB.w;
#pragma unroll
        for (int off = 1; off < 8; off <<= 1) {
            elA += __shfl_xor(elA, off); erA += __shfl_xor(erA, off);
            elB += __shfl_xor(elB, off); erB += __shfl_xor(erB, off);
        }
        if (ok && tx == 0) {
            elsc2[row * 4 + 0] = make_float2(elA, scale);
            elsc2[row * 4 + 2] = make_float2(elB, scale);
            er_nh[row * 4 + 0] = erA;
            er_nh[row * 4 + 2] = erB;
        }
        if (ok && tx == 8) {
            elsc2[row * 4 + 1] = make_float2(elA, scale);
            elsc2[row * 4 + 3] = make_float2(elB, scale);
            er_nh[row * 4 + 1] = erA;
            er_nh[row * 4 + 3] = erB;
        }
    }
}

// =========================================================================
// k_agg1P: layer-1 aggregation + fused P-projection, int8 feat (r6 version
// — best measured). wave = 4 nodes x 16 lanes; full ELL row in regs;
// per-group deg bound; 8-deep gather batches. Refuted variants: 16-deep
// (r2, wave-max waste), A/B pipeline (r7, neutral-negative), two-pass
// L2-blocking (r10, -10us: gathers are latency-hidden, not L2-miss-bound).
// =========================================================================
__global__ __launch_bounds__(256) void k_agg1P(
    const unsigned* __restrict__ fq8, const float2* __restrict__ elsc2,
    const float* __restrict__ er_nh, const unsigned short* __restrict__ ell,
    const int* __restrict__ cnt, const float* __restrict__ b1,
    const float* __restrict__ WfT, float2* __restrict__ Pag,
    float* __restrict__ er2, int N) {
    __shared__ float sWf[12 * 144];
    for (int i = threadIdx.x; i < 1536; i += 256)
        sWf[swz(i >> 7, i & 127)] = WfT[i];
    __syncthreads();
    const int wave = threadIdx.x >> 6, lane = threadIdx.x & 63;
    const int nsub = lane >> 4, q = lane & 15, h = q >> 2;
    const int wbase = q * 8 + (q >> 2) * 4;
    const uint2* fq2 = (const uint2*)fq8;

    const int n = blockIdx.x * 16 + wave * 4 + nsub;
    const bool nok = n < N;
    const int nc = nok ? n : (N - 1);
    int deg = nok ? cnt[nc * CS] : 0; if (deg > CAP) deg = CAP;
    float er = nok ? er_nh[nc * 4 + h] : 0.f;
    const unsigned short* row = ell + (size_t)nc * CAP;
    uint2 rv = ((const uint2*)row)[q];   // entries 4q..4q+3 of this node's row

    float acc[8] = {0.f, 0.f, 0.f, 0.f, 0.f, 0.f, 0.f, 0.f};
    float den = 0.f, wss = 0.f;
    for (int j0 = 0; j0 < deg; j0 += 8) {
        int sv[8]; float2 esv[8]; uint2 fv[8];
#pragma unroll
        for (int v = 0; v < 8; v++) {
            int wrd = __shfl((int)((v & 2) ? rv.y : rv.x),
                             (lane & 48) | ((j0 >> 2) + (v >> 2)));
            int s = (v & 1) ? ((wrd >> 16) & 0xffff) : (wrd & 0xffff);
            sv[v] = (j0 + v < deg) ? s : 0;
        }
#pragma unroll
        for (int v = 0; v < 8; v++) esv[v] = elsc2[sv[v] * 4 + h];
#pragma unroll
        for (int v = 0; v < 8; v++) fv[v] = fq2[(size_t)sv[v] * 16 + q];
#pragma unroll
        for (int v = 0; v < 8; v++) {
            bool valid = (j0 + v) < deg;
            float e = esv[v].x + er;
            e = fmaxf(e, LEAK * e);
            float w = valid ? __expf(e) : 0.f;
            float ws = w * esv[v].y;
            unsigned ua = fv[v].x, ub = fv[v].y;
            acc[0] += ws * (float)(ua & 0xff);
            acc[1] += ws * (float)((ua >> 8) & 0xff);
            acc[2] += ws * (float)((ua >> 16) & 0xff);
            acc[3] += ws * (float)(ua >> 24);
            acc[4] += ws * (float)(ub & 0xff);
            acc[5] += ws * (float)((ub >> 8) & 0xff);
            acc[6] += ws * (float)((ub >> 16) & 0xff);
            acc[7] += ws * (float)(ub >> 24);
            den += w; wss += ws;
        }
    }
    float inv = (den > 0.f) ? (1.f / den) : 0.f;
    float off128 = 128.f * wss;
    float4 b1a = ((const float4*)b1)[q * 2];
    float4 b1b = ((const float4*)b1)[q * 2 + 1];
    float hv[8];
    hv[0] = fmaxf((acc[0] - off128) * inv + b1a.x, 0.f);
    hv[1] = fmaxf((acc[1] - off128) * inv + b1a.y, 0.f);
    hv[2] = fmaxf((acc[2] - off128) * inv + b1a.z, 0.f);
    hv[3] = fmaxf((acc[3] - off128) * inv + b1a.w, 0.f);
    hv[4] = fmaxf((acc[4] - off128) * inv + b1b.x, 0.f);
    hv[5] = fmaxf((acc[5] - off128) * inv + b1b.y, 0.f);
    hv[6] = fmaxf((acc[6] - off128) * inv + b1b.z, 0.f);
    hv[7] = fmaxf((acc[7] - off128) * inv + b1b.w, 0.f);
    float p[12];
#pragma unroll
    for (int c = 0; c < 12; c++) {
        const float* wr = sWf + c * 144 + wbase;
        float4 wa = *(const float4*)wr;
        float4 wb = *(const float4*)(wr + 4);
        p[c] = hv[0] * wa.x + hv[1] * wa.y + hv[2] * wa.z + hv[3] * wa.w
             + hv[4] * wb.x + hv[5] * wb.y + hv[6] * wb.z + hv[7] * wb.w;
    }
#pragma unroll
    for (int off = 1; off < 16; off <<= 1) {
#pragma unroll
        for (int c = 0; c < 12; c++) p[c] += __shfl_xor(p[c], off);
    }
    if (nok) {
        if (q < 4) Pag[(size_t)n * 4 + q] = make_float2(p[q], p[8 + q]);
        else if (q < 8) er2[(size_t)n * 4 + (q - 4)] = p[q];
    }
}

// =========================================================================
// k_agg2: thread per (node, head); full row in regs (r6 version).
// Statically-indexed unrolled batch loop.
// =========================================================================
__global__ __launch_bounds__(256) void k_agg2(
    const float2* __restrict__ Pag, const float* __restrict__ er2,
    const unsigned short* __restrict__ ell, const int* __restrict__ cnt,
    const float* __restrict__ bc, const float* __restrict__ fcb,
    float* __restrict__ out, int N) {
    int idx = blockIdx.x * 256 + threadIdx.x;
    int n = idx >> 2, h = idx & 3;
    if (n >= N) return;
    int deg = cnt[n * CS]; if (deg > CAP) deg = CAP;
    float er = er2[(size_t)n * 4 + h];
    const uint4* row4 = (const uint4*)(ell + (size_t)n * CAP);
    uint4 rv[8];
#pragma unroll
    for (int i = 0; i < 8; i++) rv[i] = row4[i];   // full row: 64 entries

    float num = 0.f, den = 0.f;
#pragma unroll
    for (int b8 = 0; b8 < 8; ++b8) {
        int j0 = b8 * 8;
        if (j0 >= deg) break;
        int sv[8];
#pragma unroll
        for (int v = 0; v < 8; v++) {
            unsigned wrd = ((v >> 1) == 0) ? rv[b8].x
                         : ((v >> 1) == 1) ? rv[b8].y
                         : ((v >> 1) == 2) ? rv[b8].z : rv[b8].w;
            int s = (v & 1) ? (int)(wrd >> 16) : (int)(wrd & 0xffffu);
            sv[v] = (j0 + v < deg) ? s : 0;
        }
        float2 g[8];
#pragma unroll
        for (int v = 0; v < 8; v++) g[v] = Pag[(size_t)sv[v] * 4 + h];
#pragma unroll
        for (int v = 0; v < 8; v++) {
            if (j0 + v < deg) {
                float e = g[v].x + er; e = fmaxf(e, LEAK * e);
                float w = __expf(e);
                num += w * g[v].y; den += w;
            }
        }
    }
    float r = (den > 0.f) ? (num / den) : 0.f;
    r += bc[h];
    r += __shfl_xor(r, 1);
    r += __shfl_xor(r, 2);
    if (h == 0) out[n] = 0.25f * r + fcb[0];
}

extern "C" void kernel_launch(void* const* d_in, const int* in_sizes, int n_in,
                              void* d_out, int out_size, void* d_ws, size_t ws_size,
                              hipStream_t stream) {
    const float* x   = (const float*)d_in[0];
    const int* src   = (const int*)d_in[1];
    const int* dst   = (const int*)d_in[2];
    const float* W1  = (const float*)d_in[3];
    const float* al1 = (const float*)d_in[4];
    const float* ar1 = (const float*)d_in[5];
    const float* b1  = (const float*)d_in[6];
    const float* W2  = (const float*)d_in[7];
    const float* al2 = (const float*)d_in[8];
    const float* ar2 = (const float*)d_in[9];
    const float* b2  = (const float*)d_in[10];
    const float* fcW = (const float*)d_in[11];
    const float* fcb = (const float*)d_in[12];
    float* out = (float*)d_out;

    const int N = in_sizes[0] / 128;   // 50000 (< 65536, required for ushort ELL/pk)
    const int E = in_sizes[1];

    char* w = (char*)d_ws;
    size_t off = 0;
    auto alloc = [&](size_t bytes) {
        void* p = w + off;
        off = (off + bytes + 255) & ~(size_t)255;
        return p;
    };
    unsigned* fq8  = (unsigned*)alloc((size_t)N * 32 * 4);   // int8 [N][128], 6.4 MB
    float2* elsc2  = (float2*)alloc((size_t)N * 4 * 8);      // {el_h, scale}
    float* er_nh   = (float*)alloc((size_t)N * 4 * 4);
    float2* Pag    = (float2*)alloc((size_t)N * 4 * 8);
    float* er2     = (float*)alloc((size_t)N * 4 * 4);
    float* WfT     = (float*)alloc((size_t)(12 * 128 + 4) * 4);
    float* bc      = WfT + 12 * 128;
    int* cnt       = (int*)alloc((size_t)N * CS * 4);        // padded: 64B/node
    unsigned short* ell = (unsigned short*)alloc((size_t)N * CAP * 2);
    unsigned* pk   = (unsigned*)alloc((size_t)E * 4);        // dst<<16|src, 3.2 MB

    const int zb = (N * (CS / 4) + 255) / 256;   // int4 stores over N*CS ints
    const int pkb = (E / 4 + 255) / 256;         // pack blocks
    const int gtiles = (N + 63) / 64;            // 64-row GEMM tiles
    const int R = 256;                           // ELL ranks (256 ELL octets)
    const int GO = (gtiles + 7) / 8;             // GEMM octets
    const int T = R + GO;                        // total octets

    k0<<<zb + pkb + 8, 256, 0, stream>>>(
        cnt, src, dst, pk, W2, al2, ar2, fcW, b2, WfT, bc, N, E, zb, pkb);
    k_eg<<<8 * T, 256, 0, stream>>>(
        x, W1, al1, ar1, elsc2, er_nh, fq8,
        pk, cnt, ell, N, E, R, GO, T);
    k_agg1P<<<(N + 15) / 16, 256, 0, stream>>>(
        fq8, elsc2, er_nh, ell, cnt, b1, WfT, Pag, er2, N);
    k_agg2<<<(N * 4 + 255) / 256, 256, 0, stream>>>(
        Pag, er2, ell, cnt, bc, fcb, out, N);
}